// Round 6
// baseline (204.411 us; speedup 1.0000x reference)
//
#include <hip/hip_runtime.h>
#include <hip/hip_bf16.h>

// Sparse GAT layer, gather-based:
//   h = X @ W  via bf16 MFMA (W pre-packed to B-frags); s1/s2 fused in epilogue;
//              src-histogram fused as grid-stride epilogue
//   CSR build by src: 2-level scan (add-back fused into consumers)
//   scatter dst-only (4B); ee recomputed in aggregate (s1 uniform + s2 broadcast)
//   per-node wave gather, 16 lanes/row, 4 edges/iter, 2-deep load pipeline
//   out = elu(h'/rs) fused into the gather epilogue

constexpr int D = 128;

typedef __attribute__((ext_vector_type(8))) short bf16x8;   // 8 bf16 = 4 VGPRs
typedef __attribute__((ext_vector_type(4))) float f32x4;

__device__ __forceinline__ short f2bf(float f) {
    unsigned u = __float_as_uint(f);
    unsigned r = (u + 0x7fffu + ((u >> 16) & 1u)) >> 16;    // RNE
    return (short)r;
}
__device__ __forceinline__ float bf2f(short b) {
    return __uint_as_float(((unsigned)(unsigned short)b) << 16);
}

// Pack W into B-fragment order for mfma_f32_16x16x32_bf16, and zero counts.
// bw[((s*8 + t)*64 + lane)*8 + j] = W[k][n],  k = s*32 + (lane>>4)*8 + j,
//                                            n = t*16 + (lane&15)
__global__ __launch_bounds__(256) void prep_w_zero(const float* __restrict__ W,
                                                   short* __restrict__ bw,
                                                   int* __restrict__ counts, int N) {
    const int tid = blockIdx.x * 256 + threadIdx.x;
    if (tid < 2048) {
        const int l = tid & 63, st = tid >> 6;
        const int s = st >> 3, t = st & 7;
        const int n = t * 16 + (l & 15);
        const int q = l >> 4;
#pragma unroll
        for (int j = 0; j < 8; ++j) {
            const int k = s * 32 + q * 8 + j;
            bw[tid * 8 + j] = f2bf(W[k * D + n]);
        }
    }
    for (int i = tid; i < N; i += gridDim.x * 256) counts[i] = 0;
}

// One wave = 16 rows x 128 cols. 4 k-steps x 8 n-tiles of 16x16x32 MFMA.
// Epilogue: (a) h store, (b) s1/s2 in-register reduction,
//           (c) grid-stride src histogram (independent work, overlaps).
__global__ __launch_bounds__(256) void gemm_mfma(const float* __restrict__ X,
                                                 const short* __restrict__ bw,
                                                 const float* __restrict__ a,
                                                 short* __restrict__ h,
                                                 float* __restrict__ s1,
                                                 float* __restrict__ s2,
                                                 const int* __restrict__ src,
                                                 int* __restrict__ counts,
                                                 int N, int E) {
    const int wave = threadIdx.x >> 6, lane = threadIdx.x & 63;
    const int r0 = blockIdx.x * 64 + wave * 16;
    const int m = lane & 15, q = lane >> 4;
    const int arow = r0 + m;
    const bool rowok = arow < N;
    const float* xp = X + (size_t)arow * D + q * 8;

    f32x4 acc[8] = {};
#pragma unroll
    for (int s = 0; s < 4; ++s) {
        float4 xa = {0, 0, 0, 0}, xb = {0, 0, 0, 0};
        if (rowok) {
            xa = *(const float4*)(xp + s * 32);
            xb = *(const float4*)(xp + s * 32 + 4);
        }
        bf16x8 af;
        af[0] = f2bf(xa.x); af[1] = f2bf(xa.y); af[2] = f2bf(xa.z); af[3] = f2bf(xa.w);
        af[4] = f2bf(xb.x); af[5] = f2bf(xb.y); af[6] = f2bf(xb.z); af[7] = f2bf(xb.w);
#pragma unroll
        for (int t = 0; t < 8; ++t) {
            bf16x8 bf = *(const bf16x8*)(bw + ((s * 8 + t) * 64 + lane) * 8);
            acc[t] = __builtin_amdgcn_mfma_f32_16x16x32_bf16(af, bf, acc[t], 0, 0, 0);
        }
    }
    // per-lane a1/a2 values for this lane's columns (c = t*16 + m)
    float a1v[8], a2v[8];
#pragma unroll
    for (int t = 0; t < 8; ++t) {
        a1v[t] = a[t * 16 + m];
        a2v[t] = a[D + t * 16 + m];
    }
    // C layout: col = t*16 + (lane&15), row = r0 + (lane>>4)*4 + i
    float p1[4] = {0, 0, 0, 0}, p2[4] = {0, 0, 0, 0};
#pragma unroll
    for (int t = 0; t < 8; ++t) {
#pragma unroll
        for (int i = 0; i < 4; ++i) {
            const int row = r0 + q * 4 + i;
            const short hb = f2bf(acc[t][i]);
            if (row < N) h[(size_t)row * D + t * 16 + m] = hb;   // raw bf16 bits
            const float hr = bf2f(hb);
            p1[i] += hr * a1v[t];
            p2[i] += hr * a2v[t];
        }
    }
    // reduce p1/p2 across the 16 lanes of this quad (same q, all m)
#pragma unroll
    for (int off = 1; off < 16; off <<= 1) {
#pragma unroll
        for (int i = 0; i < 4; ++i) {
            p1[i] += __shfl_xor(p1[i], off);
            p2[i] += __shfl_xor(p2[i], off);
        }
    }
    if (m < 4) {
        const int row = r0 + q * 4 + m;
        if (row < N) {
            const float v1 = (m == 0) ? p1[0] : (m == 1) ? p1[1] : (m == 2) ? p1[2] : p1[3];
            const float v2 = (m == 0) ? p2[0] : (m == 1) ? p2[1] : (m == 2) ? p2[2] : p2[3];
            s1[row] = v1;
            s2[row] = v2;
        }
    }
    // fused src histogram (grid-stride; independent of the GEMM above)
    const int stride = gridDim.x * 256;
    for (int e = blockIdx.x * 256 + threadIdx.x; e < E; e += stride)
        atomicAdd(&counts[src[e]], 1);
}

// pass 1: each block scans its 1024-chunk (local-exclusive) + block total
__global__ __launch_bounds__(256) void scan_block(const int* __restrict__ counts,
                                                  int* __restrict__ offsets,
                                                  int* __restrict__ blocksums, int N) {
    __shared__ int lsum[256];
    const int b = blockIdx.x, t = threadIdx.x;
    const int i0 = b * 1024 + t * 4;
    int c[4];
#pragma unroll
    for (int j = 0; j < 4; ++j) c[j] = (i0 + j < N) ? counts[i0 + j] : 0;
    lsum[t] = c[0] + c[1] + c[2] + c[3];
    __syncthreads();
    for (int off = 1; off < 256; off <<= 1) {
        int v = (t >= off) ? lsum[t - off] : 0;
        __syncthreads();
        lsum[t] += v;
        __syncthreads();
    }
    int run = (t == 0) ? 0 : lsum[t - 1];
#pragma unroll
    for (int j = 0; j < 4; ++j) {
        if (i0 + j < N) offsets[i0 + j] = run;
        run += c[j];
    }
    if (t == 255) blocksums[b] = lsum[255];
}

// pass 2: single block scans (<=256) block sums -> exclusive block prefixes
__global__ __launch_bounds__(256) void scan_top(const int* __restrict__ blocksums,
                                                int* __restrict__ blockpref, int G) {
    __shared__ int lsum[256];
    const int t = threadIdx.x;
    int v = (t < G) ? blocksums[t] : 0;
    lsum[t] = v;
    __syncthreads();
    for (int off = 1; off < 256; off <<= 1) {
        int u = (t >= off) ? lsum[t - off] : 0;
        __syncthreads();
        lsum[t] += u;
        __syncthreads();
    }
    if (t < G) blockpref[t] = lsum[t] - v;   // exclusive
}

// scatter dst into CSR. Global pos = local atomic + block prefix.
// (post-scatter, offsets[n] == local inclusive prefix)
__global__ __launch_bounds__(256) void scatter_edges(
    const int* __restrict__ src, const int* __restrict__ dst,
    int* __restrict__ offsets, const int* __restrict__ blockpref,
    int* __restrict__ csrd, int E) {
    const int e = blockIdx.x * 256 + threadIdx.x;
    if (e >= E) return;
    const int s = src[e];
    const int pos = atomicAdd(&offsets[s], 1) + blockpref[s >> 10];
    csrd[pos] = dst[e];
}

// one wave per node, 16 lanes/row, 4 edges/iter, 2-deep software pipeline.
// lane = g*16 + m: group g handles edge k0+g, cols m*8..m*8+7 (one bf16x8 load).
// ee recomputed here: s1[n] wave-uniform + s2[dst] broadcast gather.
__global__ __launch_bounds__(256) void aggregate(
    const int* __restrict__ csrd, const int* __restrict__ offsets,
    const int* __restrict__ blockpref,
    const float* __restrict__ s1, const float* __restrict__ s2,
    const short* __restrict__ h, float* __restrict__ out, int N) {
    const int n    = blockIdx.x * 4 + (threadIdx.x >> 6);
    const int lane = threadIdx.x & 63;
    if (n >= N) return;
    const int g = lane >> 4, m = lane & 15;
    const int beg = (n == 0) ? 0 : offsets[n - 1] + blockpref[(n - 1) >> 10];
    const int end = offsets[n] + blockpref[n >> 10];
    const float s1n = s1[n];

    // 2-deep pipeline: d is csr 2 iters ahead, s2 value 1 iter ahead.
    int   d0  = csrd[min(beg + g, end - 1)];
    int   d1  = csrd[min(beg + 4 + g, end - 1)];
    float s20 = s2[d0];

    float acc[8] = {};
    float rs = 0.f;
    for (int k0 = beg; k0 < end; k0 += 4) {
        const int   d2  = csrd[min(k0 + 8 + g, end - 1)];   // prefetch (clamped, safe)
        const float s21 = s2[d1];
        const bf16x8 row = *(const bf16x8*)(h + (size_t)d0 * D + m * 8);
        float sc = s1n + s20;
        sc = sc > 0.f ? sc : 0.2f * sc;           // LeakyReLU(0.2)
        float ee = __expf(sc);
        if (k0 + g >= end) ee = 0.f;              // tail mask
#pragma unroll
        for (int j = 0; j < 8; ++j)
            acc[j] += ee * bf2f(row[j]);
        rs += ee;
        d0 = d1; d1 = d2; s20 = s21;
    }
    // combine the 4 edge-groups (lanes l, l^16, l^32, l^48 share the same m)
#pragma unroll
    for (int off = 16; off <= 32; off <<= 1) {
        rs += __shfl_xor(rs, off);
#pragma unroll
        for (int j = 0; j < 8; ++j) acc[j] += __shfl_xor(acc[j], off);
    }
    if (g == 0) {
        const float inv = 1.f / rs;   // every node has a self-loop => rs > 0
        float o[8];
#pragma unroll
        for (int j = 0; j < 8; ++j) {
            float v = acc[j] * inv;
            o[j] = v > 0.f ? v : expm1f(v);
        }
        float* op = out + (size_t)n * D + m * 8;
        *(float4*)op       = make_float4(o[0], o[1], o[2], o[3]);
        *(float4*)(op + 4) = make_float4(o[4], o[5], o[6], o[7]);
    }
}

extern "C" void kernel_launch(void* const* d_in, const int* in_sizes, int n_in,
                              void* d_out, int out_size, void* d_ws, size_t ws_size,
                              hipStream_t stream) {
    const float* X    = (const float*)d_in[0];
    const int*   edge = (const int*)d_in[1];   // [2, E] int32
    const float* W    = (const float*)d_in[2];
    const float* a    = (const float*)d_in[3];
    float* out = (float*)d_out;

    const int N = in_sizes[0] / D;
    const int E = in_sizes[1] / 2;
    const int* src = edge;
    const int* dst = edge + E;

    // workspace layout (16B-aligned slabs): ~17 MB total
    char* ws = (char*)d_ws;
    short* h     = (short*)ws; ws += (size_t)N * D * sizeof(short);   // 12.8 MB (bf16 bits)
    int* csrd    = (int*)ws;   ws += (size_t)E * sizeof(int);         // 2.76 MB
    short* bw    = (short*)ws; ws += 2048 * 8 * sizeof(short);        // 32 KB B-frag table
    float* s1    = (float*)ws; ws += (size_t)N * sizeof(float);
    float* s2    = (float*)ws; ws += (size_t)N * sizeof(float);
    int* counts  = (int*)ws;   ws += (size_t)N * sizeof(int);
    int* offsets = (int*)ws;   ws += (size_t)(N + 1) * sizeof(int);
    int* blocksums = (int*)ws; ws += 256 * sizeof(int);
    int* blockpref = (int*)ws; ws += 256 * sizeof(int);

    const int Gs = (N + 1023) / 1024;   // scan blocks (49 for N=50000)

    prep_w_zero<<<64, 256, 0, stream>>>(W, bw, counts, N);
    gemm_mfma<<<(N + 63) / 64, 256, 0, stream>>>(X, bw, a, h, s1, s2, src, counts, N, E);
    scan_block<<<Gs, 256, 0, stream>>>(counts, offsets, blocksums, N);
    scan_top<<<1, 256, 0, stream>>>(blocksums, blockpref, Gs);
    scatter_edges<<<(E + 255) / 256, 256, 0, stream>>>(src, dst, offsets, blockpref, csrd, E);
    aggregate<<<(N + 3) / 4, 256, 0, stream>>>(csrd, offsets, blockpref, s1, s2, h, out, N);
}